// Round 9
// baseline (169.964 us; speedup 1.0000x reference)
//
#include <hip/hip_runtime.h>

typedef short short8 __attribute__((ext_vector_type(8)));
typedef _Float16 half8 __attribute__((ext_vector_type(8)));
typedef float floatx4 __attribute__((ext_vector_type(4)));
typedef __attribute__((address_space(1))) const void gvoid;
typedef __attribute__((address_space(3))) void svoid;

#define SCALE_POS 2.0f
#define SCALE_NEG 40.0f
#define THRESH 0.5f
#define MARGIN 0.1f
#define EPSV 1e-5f

__device__ __forceinline__ unsigned short f2bf(float f) {
    unsigned u = __float_as_uint(f);
    u += 0x7fffu + ((u >> 16) & 1u);   // round-to-nearest-even
    return (unsigned short)(u >> 16);
}
// order-preserving float<->uint map (no NaNs present)
__device__ __forceinline__ unsigned f2ord(float f) {
    unsigned u = __float_as_uint(f);
    return (u & 0x80000000u) ? ~u : (u | 0x80000000u);
}
__device__ __forceinline__ float ord2f(unsigned e) {
    unsigned v = (e & 0x80000000u) ? (e & 0x7fffffffu) : ~e;
    return __uint_as_float(v);
}

#define ORD_POS_INF 0xff800000u   // f2ord(+inf)
#define ORD_NEG_INF 0x007fffffu   // f2ord(-inf)

// ---- kernel 1: fp32 -> bf16 cast + stat/counter init ----
__global__ void k_init(const float* __restrict__ feats,
                       unsigned short* __restrict__ fb16,
                       unsigned* __restrict__ minp, unsigned* __restrict__ maxn,
                       float* __restrict__ psum, float* __restrict__ nsum,
                       unsigned* __restrict__ cnts,
                       int total4, int B) {
    int i = blockIdx.x * blockDim.x + threadIdx.x;
    if (i < total4) {
        float4 v = ((const float4*)feats)[i];
        ushort4 o;
        o.x = f2bf(v.x); o.y = f2bf(v.y); o.z = f2bf(v.z); o.w = f2bf(v.w);
        ((ushort4*)fb16)[i] = o;
    }
    if (i < B) {
        minp[i] = ORD_POS_INF;
        maxn[i] = ORD_NEG_INF;
        psum[i] = 0.f;
        nsum[i] = 0.f;
    }
    if (i < 64) cnts[i] = 0;   // [1] = sum2f done counter
}

// =====================================================================
// kernel 2: symmetric GEMM over 128x64 HALF-tiles.
// Each upper-tri 128x128 tile (rb<=cb) splits into h=0/1 column halves:
// 1056 blocks x 128 thr (2 waves). Per CU: ~4.1 INDEPENDENT barrier
// groups, each wave a full 64x64 worker (16 MFMA/wave/iter) — R1's
// proven regime (R1=17 tiles/us vs R2/R7/R8's 9-10 at 2 groups/CU).
// Diagonal halves: row-direction stats only (all ordered pairs present).
// Off-diag halves: row + col (symmetry) stats. fp16 store for pass 2.
// =====================================================================
__global__ void __launch_bounds__(128, 2)
k_gemm_h(const unsigned short* __restrict__ fb16,
         const int* __restrict__ labels,
         unsigned* __restrict__ minp_ord,
         unsigned* __restrict__ maxn_ord,
         _Float16* __restrict__ simh,
         int D, int nb) {
    __shared__ __align__(16) unsigned short As[128 * 32];  // 8 KB
    __shared__ __align__(16) unsigned short Bs[64 * 32];   // 4 KB
    __shared__ int labR[128], labC[64];

    const int bid = blockIdx.x;
    int t = bid >> 1;
    const int h = bid & 1;
    int rb = 0, rem = t;
    while (rem >= nb - rb) { rem -= nb - rb; ++rb; }
    const int cb = rb + rem;
    const int rowBase = rb * 128;
    const int colBase = cb * 128 + h * 64;

    const int tid = threadIdx.x;        // 0..127
    const int lane = tid & 63;
    const int wave = tid >> 6;          // 0..1 : row half (64 rows each)
    const int q = lane >> 4;
    const int cIn = lane & 15;

    labR[tid] = labels[rowBase + tid];
    if (tid < 64) labC[tid] = labels[colBase + tid];

    // staging: 12 chunks of 1KB (16 rows x 32 cols). Wave handles 6.
    // chunks 0..7 -> As (128 A-rows), 8..11 -> Bs (64 B-rows).
    const int srow = lane >> 2;
    const int scol = (lane & 3) * 8;
    const unsigned short* gP[6];
    unsigned short* lP[6];
#pragma unroll
    for (int j = 0; j < 6; ++j) {
        const int c = wave * 6 + j;
        const int base = (c < 8) ? (rowBase + c * 16) : (colBase + (c - 8) * 16);
        gP[j] = fb16 + (size_t)(base + srow) * D + scol;
        lP[j] = ((c < 8) ? (As + c * 512) : (Bs + (c - 8) * 512)) + lane * 8;
    }

    int aOff[4], bOff[4];
#pragma unroll
    for (int i = 0; i < 4; ++i) {
        aOff[i] = (wave * 64 + i * 16 + cIn) * 32 + q * 8;
        bOff[i] = (i * 16 + cIn) * 32 + q * 8;
    }

    floatx4 acc[4][4] = {};

    const int KT = D >> 5;
    for (int kt = 0; kt < KT; ++kt) {
        const int kOff = kt * 32;
        __syncthreads();
#pragma unroll
        for (int j = 0; j < 6; ++j)
            __builtin_amdgcn_global_load_lds((gvoid*)(gP[j] + kOff), (svoid*)lP[j], 16, 0, 0);
        __syncthreads();

        short8 a[4], b[4];
#pragma unroll
        for (int i = 0; i < 4; ++i) a[i] = *(const short8*)(As + aOff[i]);
#pragma unroll
        for (int i = 0; i < 4; ++i) b[i] = *(const short8*)(Bs + bOff[i]);
#pragma unroll
        for (int i = 0; i < 4; ++i)
#pragma unroll
            for (int j = 0; j < 4; ++j)
                acc[i][j] = __builtin_amdgcn_mfma_f32_16x16x32_bf16(a[i], b[j], acc[i][j], 0, 0, 0);
    }

    int rLabv[16];
#pragma unroll
    for (int mi = 0; mi < 4; ++mi)
#pragma unroll
        for (int rr = 0; rr < 4; ++rr)
            rLabv[mi * 4 + rr] = labR[wave * 64 + mi * 16 + q * 4 + rr];
    int cLabv[4];
#pragma unroll
    for (int ni = 0; ni < 4; ++ni)
        cLabv[ni] = labC[ni * 16 + cIn];

    // ---- fp16 store: thread-major, 64 contiguous halves ----
    {
        half8* dst = (half8*)(simh + (size_t)bid * 8192 + (size_t)tid * 64);
#pragma unroll
        for (int mi = 0; mi < 4; ++mi) {
            half8 h0, h1;
#pragma unroll
            for (int ni = 0; ni < 2; ++ni)
#pragma unroll
                for (int rr = 0; rr < 4; ++rr) {
                    h0[ni * 4 + rr] = (_Float16)acc[mi][ni][rr];
                    h1[ni * 4 + rr] = (_Float16)acc[mi][ni + 2][rr];
                }
            dst[mi * 2] = h0;
            dst[mi * 2 + 1] = h1;
        }
    }

    // ---- row stats ----
#pragma unroll
    for (int mi = 0; mi < 4; ++mi)
#pragma unroll
        for (int rr = 0; rr < 4; ++rr) {
            const int rLoc = wave * 64 + mi * 16 + q * 4 + rr;
            const int rLab = rLabv[mi * 4 + rr];
            float vmin = 1e30f, vmax = -1e30f;
#pragma unroll
            for (int ni = 0; ni < 4; ++ni) {
                float s = acc[mi][ni][rr];
                if (rLab == cLabv[ni]) {
                    if (s < 1.0f - EPSV) vmin = fminf(vmin, s);
                } else {
                    vmax = fmaxf(vmax, s);
                }
            }
#pragma unroll
            for (int off = 8; off; off >>= 1) {
                vmin = fminf(vmin, __shfl_xor(vmin, off, 16));
                vmax = fmaxf(vmax, __shfl_xor(vmax, off, 16));
            }
            if (cIn == 0) {
                if (vmin < 1e30f) atomicMin(&minp_ord[rowBase + rLoc], f2ord(vmin));
                if (vmax > -1e30f) atomicMax(&maxn_ord[rowBase + rLoc], f2ord(vmax));
            }
        }

    // ---- col stats via symmetry (off-diagonal tiles only) ----
    if (rb != cb) {
#pragma unroll
        for (int ni = 0; ni < 4; ++ni) {
            const int cLab = cLabv[ni];
            float vmin = 1e30f, vmax = -1e30f;
#pragma unroll
            for (int mi = 0; mi < 4; ++mi)
#pragma unroll
                for (int rr = 0; rr < 4; ++rr) {
                    float s = acc[mi][ni][rr];
                    if (rLabv[mi * 4 + rr] == cLab) {
                        if (s < 1.0f - EPSV) vmin = fminf(vmin, s);
                    } else {
                        vmax = fmaxf(vmax, s);
                    }
                }
            vmin = fminf(vmin, __shfl_xor(vmin, 16, 64));
            vmin = fminf(vmin, __shfl_xor(vmin, 32, 64));
            vmax = fmaxf(vmax, __shfl_xor(vmax, 16, 64));
            vmax = fmaxf(vmax, __shfl_xor(vmax, 32, 64));
            if (q == 0) {
                const int cLoc = ni * 16 + cIn;
                if (vmin < 1e30f) atomicMin(&minp_ord[colBase + cLoc], f2ord(vmin));
                if (vmax > -1e30f) atomicMax(&maxn_ord[colBase + cLoc], f2ord(vmax));
            }
        }
    }
}

// =====================================================================
// kernel 3: pass 2 over half-tiles (1056 blocks x 128 thr, layout matches
// the fp16 store) + fused last-block scalar reduction.
// =====================================================================
__global__ void __launch_bounds__(128)
k_sum2f(const _Float16* __restrict__ simh,
        const int* __restrict__ labels,
        const unsigned* __restrict__ minp_ord,
        const unsigned* __restrict__ maxn_ord,
        float* __restrict__ psum, float* __restrict__ nsum,
        unsigned* __restrict__ done_cnt,
        float* __restrict__ out,
        int nb, int B) {
    __shared__ int labR[128], labC[64];
    __shared__ float mpR[128], mnR[128], mpC[64], mnC[64];
    __shared__ float red[2];
    __shared__ unsigned lastflag;

    const int bid = blockIdx.x;
    int t = bid >> 1;
    const int h = bid & 1;
    int rb = 0, rem = t;
    while (rem >= nb - rb) { rem -= nb - rb; ++rb; }
    const int cb = rb + rem;
    const int rowBase = rb * 128;
    const int colBase = cb * 128 + h * 64;

    const int tid = threadIdx.x;
    const int lane = tid & 63;
    const int wave = tid >> 6;
    const int q = lane >> 4;
    const int cIn = lane & 15;

    labR[tid] = labels[rowBase + tid];
    mpR[tid] = ord2f(minp_ord[rowBase + tid]) - MARGIN;   // neg kept if s > this
    mnR[tid] = ord2f(maxn_ord[rowBase + tid]) + MARGIN;   // pos kept if s < this
    if (tid < 64) {
        labC[tid] = labels[colBase + tid];
        mpC[tid] = ord2f(minp_ord[colBase + tid]) - MARGIN;
        mnC[tid] = ord2f(maxn_ord[colBase + tid]) + MARGIN;
    }
    __syncthreads();

    int cLabv[4];
    float mpCv[4], mnCv[4];
#pragma unroll
    for (int ni = 0; ni < 4; ++ni) {
        const int cLoc = ni * 16 + cIn;
        cLabv[ni] = labC[cLoc];
        mpCv[ni] = mpC[cLoc];
        mnCv[ni] = mnC[cLoc];
    }

    const half8* src = (const half8*)(simh + (size_t)bid * 8192 + (size_t)tid * 64);
    half8 hv[8];
#pragma unroll
    for (int v = 0; v < 8; ++v) hv[v] = src[v];

    float cps[4] = {}, cns[4] = {};
    const bool offd = (rb != cb);

#pragma unroll
    for (int mi = 0; mi < 4; ++mi)
#pragma unroll
        for (int rr = 0; rr < 4; ++rr) {
            const int rLoc = wave * 64 + mi * 16 + q * 4 + rr;
            const int rLab = labR[rLoc];
            const float gateN = mpR[rLoc];
            const float gateP = mnR[rLoc];
            float rp = 0.f, rn = 0.f;
#pragma unroll
            for (int ni = 0; ni < 4; ++ni) {
                const int idx = mi * 16 + ni * 4 + rr;
                const float s = (float)hv[idx >> 3][idx & 7];
                if (rLab == cLabv[ni]) {
                    if (s < 1.0f - EPSV) {
                        float ev = __expf(-SCALE_POS * (s - THRESH));
                        if (s < gateP) rp += ev;
                        if (offd && s < mnCv[ni]) cps[ni] += ev;
                    }
                } else {
                    float ev = __expf(SCALE_NEG * (s - THRESH));
                    if (s > gateN) rn += ev;
                    if (offd && s > mpCv[ni]) cns[ni] += ev;
                }
            }
#pragma unroll
            for (int off = 8; off; off >>= 1) {
                rp += __shfl_xor(rp, off, 16);
                rn += __shfl_xor(rn, off, 16);
            }
            if (cIn == 0) {
                if (rp != 0.f) atomicAdd(&psum[rowBase + rLoc], rp);
                if (rn != 0.f) atomicAdd(&nsum[rowBase + rLoc], rn);
            }
        }
    if (offd) {
#pragma unroll
        for (int ni = 0; ni < 4; ++ni) {
            cps[ni] += __shfl_xor(cps[ni], 16, 64);
            cps[ni] += __shfl_xor(cps[ni], 32, 64);
            cns[ni] += __shfl_xor(cns[ni], 16, 64);
            cns[ni] += __shfl_xor(cns[ni], 32, 64);
            if (q == 0) {
                const int cLoc = ni * 16 + cIn;
                if (cps[ni] != 0.f) atomicAdd(&psum[colBase + cLoc], cps[ni]);
                if (cns[ni] != 0.f) atomicAdd(&nsum[colBase + cLoc], cns[ni]);
            }
        }
    }

    // ---- last-block final reduction ----
    // __syncthreads() drains vmcnt for ALL waves -> this block's atomics
    // are complete at L2 before the increment below.
    __syncthreads();
    if (tid == 0) {
        unsigned prev = __hip_atomic_fetch_add(done_cnt, 1u, __ATOMIC_ACQ_REL,
                                               __HIP_MEMORY_SCOPE_AGENT);
        lastflag = (prev == (unsigned)(gridDim.x - 1)) ? 1u : 0u;
    }
    __syncthreads();
    if (lastflag) {
        float a = 0.f;
        for (int i = tid; i < B; i += 128) {
            float pv = atomicAdd(&psum[i], 0.0f);   // device-scope coherent read
            float nv = atomicAdd(&nsum[i], 0.0f);
            if (pv > 0.f && nv > 0.f)
                a += log1pf(pv) * (1.0f / SCALE_POS) + log1pf(nv) * (1.0f / SCALE_NEG);
        }
#pragma unroll
        for (int off = 32; off; off >>= 1) a += __shfl_down(a, off, 64);
        if ((tid & 63) == 0) red[tid >> 6] = a;
        __syncthreads();
        if (tid == 0) out[0] = (red[0] + red[1]) / (float)B;
    }
}

extern "C" void kernel_launch(void* const* d_in, const int* in_sizes, int n_in,
                              void* d_out, int out_size, void* d_ws, size_t ws_size,
                              hipStream_t stream) {
    const float* feats = (const float*)d_in[0];
    const int* labels = (const int*)d_in[1];
    const int B = in_sizes[1];            // 4096
    const int D = in_sizes[0] / B;        // 1024
    const int nb = B / 128;               // 32
    const int NT = nb * (nb + 1) / 2;     // 528
    const int NH = NT * 2;                // 1056 half-tiles
    const int total4 = B * D / 4;

    char* ws = (char*)d_ws;
    unsigned short* fb16 = (unsigned short*)ws;
    size_t off = (size_t)B * D * sizeof(unsigned short);
    unsigned* minp = (unsigned*)(ws + off); off += (size_t)B * 4;
    unsigned* maxn = (unsigned*)(ws + off); off += (size_t)B * 4;
    float* psum = (float*)(ws + off); off += (size_t)B * 4;
    float* nsum = (float*)(ws + off); off += (size_t)B * 4;
    unsigned* cnts = (unsigned*)(ws + off); off += 256;   // zeroed by k_init
    _Float16* simh = (_Float16*)(ws + ((off + 255) & ~(size_t)255));
    float* outp = (float*)d_out;

    k_init<<<(total4 + 255) / 256, 256, 0, stream>>>(feats, fb16, minp, maxn,
                                                     psum, nsum, cnts, total4, B);

    // 1056 blocks x 128 thr -> ~4.1 independent barrier-groups per CU
    k_gemm_h<<<NH, 128, 0, stream>>>(fb16, labels, minp, maxn, simh, D, nb);

    k_sum2f<<<NH, 128, 0, stream>>>(simh, labels, minp, maxn, psum, nsum,
                                    &cnts[1], outp, nb, B);
}

// Round 10
// 145.988 us; speedup vs baseline: 1.1642x; 1.1642x over previous
//
#include <hip/hip_runtime.h>

typedef short short8 __attribute__((ext_vector_type(8)));
typedef _Float16 half8 __attribute__((ext_vector_type(8)));
typedef float floatx4 __attribute__((ext_vector_type(4)));
typedef __attribute__((address_space(1))) const void gvoid;
typedef __attribute__((address_space(3))) void svoid;

#define SCALE_POS 2.0f
#define SCALE_NEG 40.0f
#define THRESH 0.5f
#define MARGIN 0.1f
#define EPSV 1e-5f

__device__ __forceinline__ unsigned short f2bf(float f) {
    unsigned u = __float_as_uint(f);
    u += 0x7fffu + ((u >> 16) & 1u);   // round-to-nearest-even
    return (unsigned short)(u >> 16);
}
// order-preserving float<->uint map (no NaNs present)
__device__ __forceinline__ unsigned f2ord(float f) {
    unsigned u = __float_as_uint(f);
    return (u & 0x80000000u) ? ~u : (u | 0x80000000u);
}
__device__ __forceinline__ float ord2f(unsigned e) {
    unsigned v = (e & 0x80000000u) ? (e & 0x7fffffffu) : ~e;
    return __uint_as_float(v);
}

#define ORD_POS_INF 0xff800000u   // f2ord(+inf)
#define ORD_NEG_INF 0x007fffffu   // f2ord(-inf)

// ---- kernel 1: fp32 -> bf16 cast + stat/counter init ----
__global__ void k_init(const float* __restrict__ feats,
                       unsigned short* __restrict__ fb16,
                       unsigned* __restrict__ minp, unsigned* __restrict__ maxn,
                       float* __restrict__ psum, float* __restrict__ nsum,
                       unsigned* __restrict__ cnts,
                       int total4, int B) {
    int i = blockIdx.x * blockDim.x + threadIdx.x;
    if (i < total4) {
        float4 v = ((const float4*)feats)[i];
        ushort4 o;
        o.x = f2bf(v.x); o.y = f2bf(v.y); o.z = f2bf(v.z); o.w = f2bf(v.w);
        ((ushort4*)fb16)[i] = o;
    }
    if (i < B) {
        minp[i] = ORD_POS_INF;
        maxn[i] = ORD_NEG_INF;
        psum[i] = 0.f;
        nsum[i] = 0.f;
    }
    if (i < 64) cnts[i] = 0;   // [1] = sum2f done counter
}

// =====================================================================
// kernel 2 (unchanged from R9 — the proven fast shape): symmetric GEMM
// over 128x64 HALF-tiles. 1056 blocks x 128 thr (2 waves, each a full
// 64x64 worker, 16 MFMA/wave/iter) -> ~4.1 independent barrier-groups
// per CU. Diagonal halves: row stats only. Off-diag: row + col stats.
// fp16 tile store for pass 2.
// =====================================================================
__global__ void __launch_bounds__(128, 2)
k_gemm_h(const unsigned short* __restrict__ fb16,
         const int* __restrict__ labels,
         unsigned* __restrict__ minp_ord,
         unsigned* __restrict__ maxn_ord,
         _Float16* __restrict__ simh,
         int D, int nb) {
    __shared__ __align__(16) unsigned short As[128 * 32];  // 8 KB
    __shared__ __align__(16) unsigned short Bs[64 * 32];   // 4 KB
    __shared__ int labR[128], labC[64];

    const int bid = blockIdx.x;
    int t = bid >> 1;
    const int h = bid & 1;
    int rb = 0, rem = t;
    while (rem >= nb - rb) { rem -= nb - rb; ++rb; }
    const int cb = rb + rem;
    const int rowBase = rb * 128;
    const int colBase = cb * 128 + h * 64;

    const int tid = threadIdx.x;        // 0..127
    const int lane = tid & 63;
    const int wave = tid >> 6;          // 0..1 : row half (64 rows each)
    const int q = lane >> 4;
    const int cIn = lane & 15;

    labR[tid] = labels[rowBase + tid];
    if (tid < 64) labC[tid] = labels[colBase + tid];

    // staging: 12 chunks of 1KB (16 rows x 32 cols). Wave handles 6.
    const int srow = lane >> 2;
    const int scol = (lane & 3) * 8;
    const unsigned short* gP[6];
    unsigned short* lP[6];
#pragma unroll
    for (int j = 0; j < 6; ++j) {
        const int c = wave * 6 + j;
        const int base = (c < 8) ? (rowBase + c * 16) : (colBase + (c - 8) * 16);
        gP[j] = fb16 + (size_t)(base + srow) * D + scol;
        lP[j] = ((c < 8) ? (As + c * 512) : (Bs + (c - 8) * 512)) + lane * 8;
    }

    int aOff[4], bOff[4];
#pragma unroll
    for (int i = 0; i < 4; ++i) {
        aOff[i] = (wave * 64 + i * 16 + cIn) * 32 + q * 8;
        bOff[i] = (i * 16 + cIn) * 32 + q * 8;
    }

    floatx4 acc[4][4] = {};

    const int KT = D >> 5;
    for (int kt = 0; kt < KT; ++kt) {
        const int kOff = kt * 32;
        __syncthreads();
#pragma unroll
        for (int j = 0; j < 6; ++j)
            __builtin_amdgcn_global_load_lds((gvoid*)(gP[j] + kOff), (svoid*)lP[j], 16, 0, 0);
        __syncthreads();

        short8 a[4], b[4];
#pragma unroll
        for (int i = 0; i < 4; ++i) a[i] = *(const short8*)(As + aOff[i]);
#pragma unroll
        for (int i = 0; i < 4; ++i) b[i] = *(const short8*)(Bs + bOff[i]);
#pragma unroll
        for (int i = 0; i < 4; ++i)
#pragma unroll
            for (int j = 0; j < 4; ++j)
                acc[i][j] = __builtin_amdgcn_mfma_f32_16x16x32_bf16(a[i], b[j], acc[i][j], 0, 0, 0);
    }

    int rLabv[16];
#pragma unroll
    for (int mi = 0; mi < 4; ++mi)
#pragma unroll
        for (int rr = 0; rr < 4; ++rr)
            rLabv[mi * 4 + rr] = labR[wave * 64 + mi * 16 + q * 4 + rr];
    int cLabv[4];
#pragma unroll
    for (int ni = 0; ni < 4; ++ni)
        cLabv[ni] = labC[ni * 16 + cIn];

    // ---- fp16 store: thread-major, 64 contiguous halves ----
    {
        half8* dst = (half8*)(simh + (size_t)bid * 8192 + (size_t)tid * 64);
#pragma unroll
        for (int mi = 0; mi < 4; ++mi) {
            half8 h0, h1;
#pragma unroll
            for (int ni = 0; ni < 2; ++ni)
#pragma unroll
                for (int rr = 0; rr < 4; ++rr) {
                    h0[ni * 4 + rr] = (_Float16)acc[mi][ni][rr];
                    h1[ni * 4 + rr] = (_Float16)acc[mi][ni + 2][rr];
                }
            dst[mi * 2] = h0;
            dst[mi * 2 + 1] = h1;
        }
    }

    // ---- row stats ----
#pragma unroll
    for (int mi = 0; mi < 4; ++mi)
#pragma unroll
        for (int rr = 0; rr < 4; ++rr) {
            const int rLoc = wave * 64 + mi * 16 + q * 4 + rr;
            const int rLab = rLabv[mi * 4 + rr];
            float vmin = 1e30f, vmax = -1e30f;
#pragma unroll
            for (int ni = 0; ni < 4; ++ni) {
                float s = acc[mi][ni][rr];
                if (rLab == cLabv[ni]) {
                    if (s < 1.0f - EPSV) vmin = fminf(vmin, s);
                } else {
                    vmax = fmaxf(vmax, s);
                }
            }
#pragma unroll
            for (int off = 8; off; off >>= 1) {
                vmin = fminf(vmin, __shfl_xor(vmin, off, 16));
                vmax = fmaxf(vmax, __shfl_xor(vmax, off, 16));
            }
            if (cIn == 0) {
                if (vmin < 1e30f) atomicMin(&minp_ord[rowBase + rLoc], f2ord(vmin));
                if (vmax > -1e30f) atomicMax(&maxn_ord[rowBase + rLoc], f2ord(vmax));
            }
        }

    // ---- col stats via symmetry (off-diagonal tiles only) ----
    if (rb != cb) {
#pragma unroll
        for (int ni = 0; ni < 4; ++ni) {
            const int cLab = cLabv[ni];
            float vmin = 1e30f, vmax = -1e30f;
#pragma unroll
            for (int mi = 0; mi < 4; ++mi)
#pragma unroll
                for (int rr = 0; rr < 4; ++rr) {
                    float s = acc[mi][ni][rr];
                    if (rLabv[mi * 4 + rr] == cLab) {
                        if (s < 1.0f - EPSV) vmin = fminf(vmin, s);
                    } else {
                        vmax = fmaxf(vmax, s);
                    }
                }
            vmin = fminf(vmin, __shfl_xor(vmin, 16, 64));
            vmin = fminf(vmin, __shfl_xor(vmin, 32, 64));
            vmax = fmaxf(vmax, __shfl_xor(vmax, 16, 64));
            vmax = fmaxf(vmax, __shfl_xor(vmax, 32, 64));
            if (q == 0) {
                const int cLoc = ni * 16 + cIn;
                if (vmin < 1e30f) atomicMin(&minp_ord[colBase + cLoc], f2ord(vmin));
                if (vmax > -1e30f) atomicMax(&maxn_ord[colBase + cLoc], f2ord(vmax));
            }
        }
    }
}

// =====================================================================
// kernel 3: pass 2, 528 blocks x 256 threads — each block handles BOTH
// halves of its tile (sub = tid>>7) against the R9 half-tile fp16 layout.
// Done-counter is RELAXED (no agent-scope release/acquire -> no per-block
// L2 writeback/invalidate; that fence was R9's 58us idle tail).
// =====================================================================
__global__ void __launch_bounds__(256)
k_sum2f(const _Float16* __restrict__ simh,
        const int* __restrict__ labels,
        const unsigned* __restrict__ minp_ord,
        const unsigned* __restrict__ maxn_ord,
        float* __restrict__ psum, float* __restrict__ nsum,
        unsigned* __restrict__ done_cnt,
        float* __restrict__ out,
        int nb, int B) {
    __shared__ int labR[128], labC[128];
    __shared__ float mpR[128], mnR[128], mpC[128], mnC[128];
    __shared__ float red[4];
    __shared__ unsigned lastflag;

    int t = blockIdx.x;
    int rb = 0, rem = t;
    while (rem >= nb - rb) { rem -= nb - rb; ++rb; }
    const int cb = rb + rem;
    const int rowBase = rb * 128;

    const int tid = threadIdx.x;
    const int sub = tid >> 7;           // which 64-col half of the tile
    const int stid = tid & 127;
    const int wave = stid >> 6;         // row half within half-tile
    const int lane = tid & 63;
    const int q = lane >> 4;
    const int cIn = lane & 15;
    const int colBase = cb * 128 + sub * 64;

    if (tid < 128) {
        labR[tid] = labels[rowBase + tid];
        mpR[tid] = ord2f(minp_ord[rowBase + tid]) - MARGIN;   // neg kept if s > this
        mnR[tid] = ord2f(maxn_ord[rowBase + tid]) + MARGIN;   // pos kept if s < this
    } else {
        const int j = tid - 128;        // 0..127 over both halves' columns
        labC[j] = labels[cb * 128 + j];
        mpC[j] = ord2f(minp_ord[cb * 128 + j]) - MARGIN;
        mnC[j] = ord2f(maxn_ord[cb * 128 + j]) + MARGIN;
    }
    __syncthreads();

    int cLabv[4];
    float mpCv[4], mnCv[4];
#pragma unroll
    for (int ni = 0; ni < 4; ++ni) {
        const int j = sub * 64 + ni * 16 + cIn;
        cLabv[ni] = labC[j];
        mpCv[ni] = mpC[j];
        mnCv[ni] = mnC[j];
    }

    const half8* src = (const half8*)(simh + (size_t)(2 * t + sub) * 8192 + (size_t)stid * 64);
    half8 hv[8];
#pragma unroll
    for (int v = 0; v < 8; ++v) hv[v] = src[v];

    float cps[4] = {}, cns[4] = {};
    const bool offd = (rb != cb);

#pragma unroll
    for (int mi = 0; mi < 4; ++mi)
#pragma unroll
        for (int rr = 0; rr < 4; ++rr) {
            const int rLoc = wave * 64 + mi * 16 + q * 4 + rr;
            const int rLab = labR[rLoc];
            const float gateN = mpR[rLoc];
            const float gateP = mnR[rLoc];
            float rp = 0.f, rn = 0.f;
#pragma unroll
            for (int ni = 0; ni < 4; ++ni) {
                const int idx = mi * 16 + ni * 4 + rr;
                const float s = (float)hv[idx >> 3][idx & 7];
                if (rLab == cLabv[ni]) {
                    if (s < 1.0f - EPSV) {
                        float ev = __expf(-SCALE_POS * (s - THRESH));
                        if (s < gateP) rp += ev;
                        if (offd && s < mnCv[ni]) cps[ni] += ev;
                    }
                } else {
                    float ev = __expf(SCALE_NEG * (s - THRESH));
                    if (s > gateN) rn += ev;
                    if (offd && s > mpCv[ni]) cns[ni] += ev;
                }
            }
#pragma unroll
            for (int off = 8; off; off >>= 1) {
                rp += __shfl_xor(rp, off, 16);
                rn += __shfl_xor(rn, off, 16);
            }
            if (cIn == 0) {
                if (rp != 0.f) atomicAdd(&psum[rowBase + rLoc], rp);
                if (rn != 0.f) atomicAdd(&nsum[rowBase + rLoc], rn);
            }
        }
    if (offd) {
#pragma unroll
        for (int ni = 0; ni < 4; ++ni) {
            cps[ni] += __shfl_xor(cps[ni], 16, 64);
            cps[ni] += __shfl_xor(cps[ni], 32, 64);
            cns[ni] += __shfl_xor(cns[ni], 16, 64);
            cns[ni] += __shfl_xor(cns[ni], 32, 64);
            if (q == 0) {
                const int cLoc = ni * 16 + cIn;
                if (cps[ni] != 0.f) atomicAdd(&psum[colBase + cLoc], cps[ni]);
                if (cns[ni] != 0.f) atomicAdd(&nsum[colBase + cLoc], cns[ni]);
            }
        }
    }

    // ---- last-block final reduction (RELAXED counter — no fences) ----
    // __syncthreads() drains vmcnt for ALL waves -> this block's psum/nsum
    // atomics are complete at the coherence point before the increment.
    __syncthreads();
    if (tid == 0) {
        unsigned prev = __hip_atomic_fetch_add(done_cnt, 1u, __ATOMIC_RELAXED,
                                               __HIP_MEMORY_SCOPE_AGENT);
        lastflag = (prev == (unsigned)(gridDim.x - 1)) ? 1u : 0u;
    }
    __syncthreads();
    if (lastflag) {
        float a = 0.f;
        for (int i = tid; i < B; i += 256) {
            float pv = atomicAdd(&psum[i], 0.0f);   // coherent returning atomic
            float nv = atomicAdd(&nsum[i], 0.0f);
            if (pv > 0.f && nv > 0.f)
                a += log1pf(pv) * (1.0f / SCALE_POS) + log1pf(nv) * (1.0f / SCALE_NEG);
        }
#pragma unroll
        for (int off = 32; off; off >>= 1) a += __shfl_down(a, off, 64);
        if ((tid & 63) == 0) red[tid >> 6] = a;
        __syncthreads();
        if (tid == 0) out[0] = (red[0] + red[1] + red[2] + red[3]) / (float)B;
    }
}

extern "C" void kernel_launch(void* const* d_in, const int* in_sizes, int n_in,
                              void* d_out, int out_size, void* d_ws, size_t ws_size,
                              hipStream_t stream) {
    const float* feats = (const float*)d_in[0];
    const int* labels = (const int*)d_in[1];
    const int B = in_sizes[1];            // 4096
    const int D = in_sizes[0] / B;        // 1024
    const int nb = B / 128;               // 32
    const int NT = nb * (nb + 1) / 2;     // 528
    const int NH = NT * 2;                // 1056 half-tiles
    const int total4 = B * D / 4;

    char* ws = (char*)d_ws;
    unsigned short* fb16 = (unsigned short*)ws;
    size_t off = (size_t)B * D * sizeof(unsigned short);
    unsigned* minp = (unsigned*)(ws + off); off += (size_t)B * 4;
    unsigned* maxn = (unsigned*)(ws + off); off += (size_t)B * 4;
    float* psum = (float*)(ws + off); off += (size_t)B * 4;
    float* nsum = (float*)(ws + off); off += (size_t)B * 4;
    unsigned* cnts = (unsigned*)(ws + off); off += 256;   // zeroed by k_init
    _Float16* simh = (_Float16*)(ws + ((off + 255) & ~(size_t)255));
    float* outp = (float*)d_out;

    k_init<<<(total4 + 255) / 256, 256, 0, stream>>>(feats, fb16, minp, maxn,
                                                     psum, nsum, cnts, total4, B);

    // 1056 blocks x 128 thr -> ~4.1 independent barrier-groups per CU
    k_gemm_h<<<NH, 128, 0, stream>>>(fb16, labels, minp, maxn, simh, D, nb);

    // 528 blocks x 256 thr, relaxed done-counter
    k_sum2f<<<NT, 256, 0, stream>>>(simh, labels, minp, maxn, psum, nsum,
                                    &cnts[1], outp, nb, B);
}